// Round 1
// baseline (102.798 us; speedup 1.0000x reference)
//
#include <hip/hip_runtime.h>

#define BATCH 8
#define NDIM 2048
#define FDIM 256
#define CH 32   // row-chunks for column-sum partials (64 rows each)

typedef float f32x4 __attribute__((ext_vector_type(4)));
typedef short bf16x8 __attribute__((ext_vector_type(8)));
typedef short bf16x4 __attribute__((ext_vector_type(4)));

__device__ __forceinline__ short f2bf(float f) {
  union { float f; unsigned u; } v{f};
  return (short)((v.u + 0x7FFFu + ((v.u >> 16) & 1u)) >> 16);  // RNE
}

__device__ __forceinline__ void gload_lds16(const void* g, void* l) {
  __builtin_amdgcn_global_load_lds(
      (const __attribute__((address_space(1))) void*)g,
      (__attribute__((address_space(3))) void*)l, 16, 0, 0);
}

// ---------------- Kernel 1: partial column sums of adj ----------------
// grid = BATCH * CH * 2 colblocks, block = 256.  part[b][ch][col]
__global__ __launch_bounds__(256) void k_colsum(const float* __restrict__ adj,
                                                float* __restrict__ part) {
  int bid = blockIdx.x;
  int cb = bid & 1;
  int ch = (bid >> 1) & (CH - 1);
  int b = bid >> 6;
  int col = cb * 1024 + threadIdx.x * 4;
  const float* p = adj + (size_t)b * NDIM * NDIM + (size_t)(ch * 64) * NDIM + col;
  f32x4 acc = {0.f, 0.f, 0.f, 0.f};
#pragma unroll 4
  for (int i = 0; i < 64; ++i) acc += *(const f32x4*)(p + (size_t)i * NDIM);
  *(f32x4*)(part + (size_t)(b * CH + ch) * NDIM + col) = acc;
}

// ---------------- Kernel 2: d = rsqrt(colsum) ----------------
__global__ __launch_bounds__(256) void k_dfin(const float* __restrict__ part,
                                              float* __restrict__ dnorm) {
  int idx = blockIdx.x * 256 + threadIdx.x;  // b*NDIM + j
  int b = idx >> 11, j = idx & (NDIM - 1);
  float s = 0.f;
#pragma unroll
  for (int c = 0; c < CH; ++c) s += part[(size_t)(b * CH + c) * NDIM + j];
  dnorm[idx] = rsqrtf(s);
}

// ---------------- Kernel 3: Wt[o][f] = bf16(W[f][o]) ----------------
// grid = 16 (4x4 tiles of 64x64), block 256
__global__ __launch_bounds__(256) void k_wt(const float* __restrict__ w,
                                            short* __restrict__ wt) {
  __shared__ float tile[64][65];
  int t = threadIdx.x;
  int bx = blockIdx.x & 3, by = blockIdx.x >> 2;
  int f0 = by * 64, o0 = bx * 64;
  int c4 = 4 * (t & 15);
#pragma unroll
  for (int q = 0; q < 4; ++q) {
    int r = (t >> 4) + 16 * q;
    f32x4 v = *(const f32x4*)(w + (size_t)(f0 + r) * FDIM + o0 + c4);
#pragma unroll
    for (int i = 0; i < 4; ++i) tile[r][c4 + i] = v[i];
  }
  __syncthreads();
#pragma unroll
  for (int q = 0; q < 4; ++q) {
    int r = (t >> 4) + 16 * q;
    bf16x4 pk;
#pragma unroll
    for (int i = 0; i < 4; ++i) pk[i] = f2bf(tile[c4 + i][r]);
    *(bf16x4*)(wt + (size_t)(o0 + r) * FDIM + f0 + c4) = pk;
  }
}

// ---------------- Kernel 4: St[b][o][m] = bf16(d[b][m] * (X @ W)[m][o]) ----
// block 256 (4 waves), tile 64 rows x 256 cols, K=256 in 8 steps of 32
__global__ __launch_bounds__(256) void k_support(const float* __restrict__ in,
                                                 const short* __restrict__ wt,
                                                 const float* __restrict__ dnorm,
                                                 short* __restrict__ st) {
  __shared__ short Al[64 * 32];
  __shared__ short Bl[256 * 32];
  int t = threadIdx.x, lane = t & 63, w = t >> 6;
  int b = blockIdx.x >> 5;
  int m0 = (blockIdx.x & 31) * 64;
  const float* inb = in + ((size_t)b * NDIM + m0) * FDIM;

  f32x4 acc[4][4];
#pragma unroll
  for (int m = 0; m < 4; ++m)
#pragma unroll
    for (int n = 0; n < 4; ++n) acc[m][n] = {0.f, 0.f, 0.f, 0.f};

  int ar = t >> 2, ac = t & 3;  // A-stage mapping: row, 8-col chunk
  for (int it = 0; it < 8; ++it) {
    int k0 = it * 32;
    // stage A (f32 -> bf16)
    {
      f32x4 v0 = *(const f32x4*)(inb + (size_t)ar * FDIM + k0 + 8 * ac);
      f32x4 v1 = *(const f32x4*)(inb + (size_t)ar * FDIM + k0 + 8 * ac + 4);
      bf16x8 p;
#pragma unroll
      for (int i = 0; i < 4; ++i) { p[i] = f2bf(v0[i]); p[4 + i] = f2bf(v1[i]); }
      *(bf16x8*)&Al[ar * 32 + 8 * ac] = p;
    }
    // stage B via global_load_lds (already bf16)
#pragma unroll
    for (int i = 0; i < 4; ++i) {
      int ss = i * 256 + t;
      int o = ss >> 2, c = ss & 3;
      gload_lds16(wt + (size_t)o * FDIM + k0 + 8 * c, &Bl[ss * 8]);
    }
    __syncthreads();
    bf16x8 af[4], bf[4];
#pragma unroll
    for (int m = 0; m < 4; ++m)
      af[m] = *(const bf16x8*)&Al[(16 * m + (lane & 15)) * 32 + (lane >> 4) * 8];
#pragma unroll
    for (int n = 0; n < 4; ++n)
      bf[n] = *(const bf16x8*)&Bl[(64 * w + 16 * n + (lane & 15)) * 32 + (lane >> 4) * 8];
#pragma unroll
    for (int m = 0; m < 4; ++m)
#pragma unroll
      for (int n = 0; n < 4; ++n)
        acc[m][n] = __builtin_amdgcn_mfma_f32_16x16x32_bf16(af[m], bf[n], acc[m][n], 0, 0, 0);
    __syncthreads();
  }
  // epilogue: scale by d[m], store transposed bf16: St[(b*256+o)*2048 + m]
#pragma unroll
  for (int m = 0; m < 4; ++m) {
    int row = m0 + 16 * m + ((lane >> 4) << 2);
    float dm[4];
#pragma unroll
    for (int j = 0; j < 4; ++j) dm[j] = dnorm[b * NDIM + row + j];
#pragma unroll
    for (int n = 0; n < 4; ++n) {
      int col = 64 * w + 16 * n + (lane & 15);
      bf16x4 pk;
#pragma unroll
      for (int j = 0; j < 4; ++j) pk[j] = f2bf(acc[m][n][j] * dm[j]);
      *(bf16x4*)(st + ((size_t)(b * FDIM + col)) * NDIM + row) = pk;
    }
  }
}

// ---------------- Kernel 5: out = d_n * (adj @ S) + bias ----------------
// block 256 (4 waves), tile 32 rows x 256 cols, K=2048 in 64 steps of 32,
// double-buffered: A reg-staged f32->bf16, B via global_load_lds from St.
__global__ __launch_bounds__(256) void k_main(const float* __restrict__ adj,
                                              const short* __restrict__ st,
                                              const float* __restrict__ dnorm,
                                              const float* __restrict__ bias,
                                              float* __restrict__ out) {
  __shared__ short Al[2][32 * 32];
  __shared__ short Bl[2][256 * 32];
  int t = threadIdx.x, lane = t & 63, w = t >> 6;
  int bid = blockIdx.x;
  int b = bid >> 6;
  int n0 = (bid & 63) * 32;
  const float* adjb = adj + (size_t)b * NDIM * NDIM + (size_t)n0 * NDIM;
  const short* stb = st + (size_t)b * FDIM * NDIM;

  f32x4 acc[2][4];
#pragma unroll
  for (int m = 0; m < 2; ++m)
#pragma unroll
    for (int n = 0; n < 4; ++n) acc[m][n] = {0.f, 0.f, 0.f, 0.f};

  int ar = t >> 3, ac = t & 7;  // A-stage: row 0..31, 4-col chunk 0..7
  f32x4 areg;

  // prologue: stage tile 0
#pragma unroll
  for (int i = 0; i < 4; ++i) {
    int ss = i * 256 + t;
    int o = ss >> 2, c = ss & 3;
    gload_lds16(stb + (size_t)o * NDIM + 8 * c, &Bl[0][ss * 8]);
  }
  areg = *(const f32x4*)(adjb + (size_t)ar * NDIM + 4 * ac);
  {
    bf16x4 p;
#pragma unroll
    for (int i = 0; i < 4; ++i) p[i] = f2bf(areg[i]);
    *(bf16x4*)&Al[0][ar * 32 + 4 * ac] = p;
  }
  __syncthreads();

  for (int it = 0; it < 64; ++it) {
    int cur = it & 1, nxt = cur ^ 1;
    if (it < 63) {
      int k0 = (it + 1) * 32;
#pragma unroll
      for (int i = 0; i < 4; ++i) {
        int ss = i * 256 + t;
        int o = ss >> 2, c = ss & 3;
        gload_lds16(stb + (size_t)o * NDIM + k0 + 8 * c, &Bl[nxt][ss * 8]);
      }
      areg = *(const f32x4*)(adjb + (size_t)ar * NDIM + k0 + 4 * ac);
    }
    bf16x8 af[2], bfv[4];
#pragma unroll
    for (int m = 0; m < 2; ++m)
      af[m] = *(const bf16x8*)&Al[cur][(16 * m + (lane & 15)) * 32 + (lane >> 4) * 8];
#pragma unroll
    for (int n = 0; n < 4; ++n)
      bfv[n] = *(const bf16x8*)&Bl[cur][(64 * w + 16 * n + (lane & 15)) * 32 + (lane >> 4) * 8];
#pragma unroll
    for (int m = 0; m < 2; ++m)
#pragma unroll
      for (int n = 0; n < 4; ++n)
        acc[m][n] = __builtin_amdgcn_mfma_f32_16x16x32_bf16(af[m], bfv[n], acc[m][n], 0, 0, 0);
    if (it < 63) {
      bf16x4 p;
#pragma unroll
      for (int i = 0; i < 4; ++i) p[i] = f2bf(areg[i]);
      *(bf16x4*)&Al[nxt][ar * 32 + 4 * ac] = p;
    }
    __syncthreads();
  }

  // epilogue: out[b][row][col] = d[b][row]*acc + bias[col]
#pragma unroll
  for (int m = 0; m < 2; ++m) {
    int row = n0 + 16 * m + ((lane >> 4) << 2);
    float dr[4];
#pragma unroll
    for (int j = 0; j < 4; ++j) dr[j] = dnorm[b * NDIM + row + j];
#pragma unroll
    for (int n = 0; n < 4; ++n) {
      int col = 64 * w + 16 * n + (lane & 15);
      float bv = bias[col];
      float* op = out + ((size_t)b * NDIM + row) * FDIM + col;
#pragma unroll
      for (int j = 0; j < 4; ++j) op[(size_t)j * FDIM] = dr[j] * acc[m][n][j] + bv;
    }
  }
}

extern "C" void kernel_launch(void* const* d_in, const int* in_sizes, int n_in,
                              void* d_out, int out_size, void* d_ws, size_t ws_size,
                              hipStream_t stream) {
  (void)in_sizes; (void)n_in; (void)out_size; (void)ws_size;
  const float* input = (const float*)d_in[0];
  const float* adj = (const float*)d_in[1];
  const float* weight = (const float*)d_in[2];
  const float* bias = (const float*)d_in[3];
  float* out = (float*)d_out;

  char* ws = (char*)d_ws;
  short* st = (short*)ws;                                      // 8 MB  (bf16 S^T)
  float* dnorm = (float*)(ws + 8ull * 1024 * 1024);            // 64 KB
  float* part = (float*)(ws + 8ull * 1024 * 1024 + 65536);     // 2 MB
  short* wt = (short*)(ws + 8ull * 1024 * 1024 + 65536 + 2ull * 1024 * 1024);  // 128 KB

  k_colsum<<<dim3(BATCH * CH * 2), dim3(256), 0, stream>>>(adj, part);
  k_dfin<<<dim3(BATCH * NDIM / 256), dim3(256), 0, stream>>>(part, dnorm);
  k_wt<<<dim3(16), dim3(256), 0, stream>>>(weight, wt);
  k_support<<<dim3(BATCH * (NDIM / 64)), dim3(256), 0, stream>>>(input, wt, dnorm, st);
  k_main<<<dim3(BATCH * (NDIM / 32)), dim3(256), 0, stream>>>(adj, st, dnorm, bias, out);
}

// Round 2
// 89.155 us; speedup vs baseline: 1.1530x; 1.1530x over previous
//
#include <hip/hip_runtime.h>

#define BATCH 8
#define NDIM 2048
#define FDIM 256
#define CH 32   // row-chunks for column-sum partials (64 rows each)

typedef float f32x4 __attribute__((ext_vector_type(4)));
typedef short bf16x8 __attribute__((ext_vector_type(8)));
typedef short bf16x4 __attribute__((ext_vector_type(4)));

__device__ __forceinline__ short f2bf(float f) {
  union { float f; unsigned u; } v{f};
  return (short)((v.u + 0x7FFFu + ((v.u >> 16) & 1u)) >> 16);  // RNE
}

__device__ __forceinline__ void gload_lds16(const void* g, void* l) {
  __builtin_amdgcn_global_load_lds(
      (const __attribute__((address_space(1))) void*)g,
      (__attribute__((address_space(3))) void*)l, 16, 0, 0);
}

// ---- Kernel 1: partial column sums of adj + bf16 conversion of adj ----
// grid = BATCH * CH * 2 colblocks, block = 256.  part[b][ch][col]
__global__ __launch_bounds__(256) void k_colsum(const float* __restrict__ adj,
                                                float* __restrict__ part,
                                                short* __restrict__ abf) {
  int bid = blockIdx.x;
  int cb = bid & 1;
  int ch = (bid >> 1) & (CH - 1);
  int b = bid >> 6;
  int col = cb * 1024 + threadIdx.x * 4;
  size_t base = (size_t)b * NDIM * NDIM + (size_t)(ch * 64) * NDIM + col;
  const float* p = adj + base;
  short* q = abf + base;
  f32x4 acc = {0.f, 0.f, 0.f, 0.f};
#pragma unroll 8
  for (int i = 0; i < 64; ++i) {
    f32x4 v = *(const f32x4*)(p + (size_t)i * NDIM);
    acc += v;
    bf16x4 pk;
#pragma unroll
    for (int j = 0; j < 4; ++j) pk[j] = f2bf(v[j]);
    *(bf16x4*)(q + (size_t)i * NDIM) = pk;
  }
  *(f32x4*)(part + (size_t)(b * CH + ch) * NDIM + col) = acc;
}

// ---------------- Kernel 2: d = rsqrt(colsum) ----------------
__global__ __launch_bounds__(256) void k_dfin(const float* __restrict__ part,
                                              float* __restrict__ dnorm) {
  int idx = blockIdx.x * 256 + threadIdx.x;  // b*NDIM + j
  float s = 0.f;
  int b = idx >> 11, j = idx & (NDIM - 1);
#pragma unroll
  for (int c = 0; c < CH; ++c) s += part[(size_t)(b * CH + c) * NDIM + j];
  dnorm[idx] = rsqrtf(s);
}

// ---------------- Kernel 3: Wt[o][f] = bf16(W[f][o]) ----------------
__global__ __launch_bounds__(256) void k_wt(const float* __restrict__ w,
                                            short* __restrict__ wt) {
  __shared__ float tile[64][65];
  int t = threadIdx.x;
  int bx = blockIdx.x & 3, by = blockIdx.x >> 2;
  int f0 = by * 64, o0 = bx * 64;
  int c4 = 4 * (t & 15);
#pragma unroll
  for (int q = 0; q < 4; ++q) {
    int r = (t >> 4) + 16 * q;
    f32x4 v = *(const f32x4*)(w + (size_t)(f0 + r) * FDIM + o0 + c4);
#pragma unroll
    for (int i = 0; i < 4; ++i) tile[r][c4 + i] = v[i];
  }
  __syncthreads();
#pragma unroll
  for (int q = 0; q < 4; ++q) {
    int r = (t >> 4) + 16 * q;
    bf16x4 pk;
#pragma unroll
    for (int i = 0; i < 4; ++i) pk[i] = f2bf(tile[c4 + i][r]);
    *(bf16x4*)(wt + (size_t)(o0 + r) * FDIM + f0 + c4) = pk;
  }
}

// ---------------- Kernel 4: St[b][o][m] = bf16(d[b][m] * (X @ W)[m][o]) ----
__global__ __launch_bounds__(256) void k_support(const float* __restrict__ in,
                                                 const short* __restrict__ wt,
                                                 const float* __restrict__ dnorm,
                                                 short* __restrict__ st) {
  __shared__ short Al[64 * 32];
  __shared__ short Bl[256 * 32];
  int t = threadIdx.x, lane = t & 63, w = t >> 6;
  int b = blockIdx.x >> 5;
  int m0 = (blockIdx.x & 31) * 64;
  const float* inb = in + ((size_t)b * NDIM + m0) * FDIM;

  f32x4 acc[4][4];
#pragma unroll
  for (int m = 0; m < 4; ++m)
#pragma unroll
    for (int n = 0; n < 4; ++n) acc[m][n] = {0.f, 0.f, 0.f, 0.f};

  int ar = t >> 2, ac = t & 3;
  for (int it = 0; it < 8; ++it) {
    int k0 = it * 32;
    {
      f32x4 v0 = *(const f32x4*)(inb + (size_t)ar * FDIM + k0 + 8 * ac);
      f32x4 v1 = *(const f32x4*)(inb + (size_t)ar * FDIM + k0 + 8 * ac + 4);
      bf16x8 p;
#pragma unroll
      for (int i = 0; i < 4; ++i) { p[i] = f2bf(v0[i]); p[4 + i] = f2bf(v1[i]); }
      *(bf16x8*)&Al[ar * 32 + 8 * ac] = p;
    }
#pragma unroll
    for (int i = 0; i < 4; ++i) {
      int ss = i * 256 + t;
      int o = ss >> 2, c = ss & 3;
      gload_lds16(wt + (size_t)o * FDIM + k0 + 8 * c, &Bl[ss * 8]);
    }
    __syncthreads();
    bf16x8 af[4], bf[4];
#pragma unroll
    for (int m = 0; m < 4; ++m)
      af[m] = *(const bf16x8*)&Al[(16 * m + (lane & 15)) * 32 + (lane >> 4) * 8];
#pragma unroll
    for (int n = 0; n < 4; ++n)
      bf[n] = *(const bf16x8*)&Bl[(64 * w + 16 * n + (lane & 15)) * 32 + (lane >> 4) * 8];
#pragma unroll
    for (int m = 0; m < 4; ++m)
#pragma unroll
      for (int n = 0; n < 4; ++n)
        acc[m][n] = __builtin_amdgcn_mfma_f32_16x16x32_bf16(af[m], bf[n], acc[m][n], 0, 0, 0);
    __syncthreads();
  }
#pragma unroll
  for (int m = 0; m < 4; ++m) {
    int row = m0 + 16 * m + ((lane >> 4) << 2);
    float dm[4];
#pragma unroll
    for (int j = 0; j < 4; ++j) dm[j] = dnorm[b * NDIM + row + j];
#pragma unroll
    for (int n = 0; n < 4; ++n) {
      int col = 64 * w + 16 * n + (lane & 15);
      bf16x4 pk;
#pragma unroll
      for (int j = 0; j < 4; ++j) pk[j] = f2bf(acc[m][n][j] * dm[j]);
      *(bf16x4*)(st + ((size_t)(b * FDIM + col)) * NDIM + row) = pk;
    }
  }
}

// ---------------- Kernel 5: out = d_n * (adj_bf16 @ St^T) + bias ----------
// 512 threads (8 waves, 2x4), BM=64 rows, BN=256 cols, BK=64, grid=256.
// Pure global_load_lds staging with source-side XOR swizzle (chunk ^= row&7);
// ds_read applies the same XOR -> conflict-free b128 fragment reads.
__global__ __launch_bounds__(512) void k_main(const short* __restrict__ abf,
                                              const short* __restrict__ st,
                                              const float* __restrict__ dnorm,
                                              const float* __restrict__ bias,
                                              float* __restrict__ out) {
  __shared__ short Al[2][64 * 64];
  __shared__ short Bl[2][256 * 64];
  int t = threadIdx.x, lane = t & 63, w = t >> 6;
  int wm = w & 1, wn = w >> 1;
  int b = blockIdx.x >> 5;
  int n0 = (blockIdx.x & 31) * 64;
  const short* ab = abf + ((size_t)b * NDIM + n0) * NDIM;
  const short* stb = st + (size_t)b * FDIM * NDIM;

  // staging source pointers (swizzled chunk: c_global = c_lds ^ (row&7))
  int srow = t >> 3;
  int schk = (t & 7) ^ (srow & 7);
  const short* asrc = ab + (size_t)srow * NDIM + 8 * schk;
  const short* bsrc = stb + (size_t)srow * NDIM + 8 * schk;

  f32x4 acc[2][4];
#pragma unroll
  for (int m = 0; m < 2; ++m)
#pragma unroll
    for (int n = 0; n < 4; ++n) acc[m][n] = {0.f, 0.f, 0.f, 0.f};

  // prologue: stage K-tile 0 into buffer 0
  gload_lds16(asrc, &Al[0][t * 8]);
#pragma unroll
  for (int i = 0; i < 4; ++i)
    gload_lds16(bsrc + (size_t)(i * 64) * NDIM, &Bl[0][(i * 512 + t) * 8]);
  __syncthreads();

  int lr = lane & 15, kg = lane >> 4, sw = lane & 7;

  for (int it = 0; it < 32; ++it) {
    int cur = it & 1, nxt = cur ^ 1;
    if (it < 31) {
      int k0 = (it + 1) * 64;
      gload_lds16(asrc + k0, &Al[nxt][t * 8]);
#pragma unroll
      for (int i = 0; i < 4; ++i)
        gload_lds16(bsrc + (size_t)(i * 64) * NDIM + k0, &Bl[nxt][(i * 512 + t) * 8]);
    }
#pragma unroll
    for (int h = 0; h < 2; ++h) {
      int kc = ((h * 4 + kg) ^ sw) * 8;
      bf16x8 af[2], bfv[4];
#pragma unroll
      for (int mf = 0; mf < 2; ++mf)
        af[mf] = *(const bf16x8*)&Al[cur][(wm * 32 + mf * 16 + lr) * 64 + kc];
#pragma unroll
      for (int nf = 0; nf < 4; ++nf)
        bfv[nf] = *(const bf16x8*)&Bl[cur][(wn * 64 + nf * 16 + lr) * 64 + kc];
#pragma unroll
      for (int mf = 0; mf < 2; ++mf)
#pragma unroll
        for (int nf = 0; nf < 4; ++nf)
          acc[mf][nf] = __builtin_amdgcn_mfma_f32_16x16x32_bf16(af[mf], bfv[nf], acc[mf][nf], 0, 0, 0);
    }
    __syncthreads();
  }

  // epilogue: out[b][row][col] = d_n[row]*acc + bias[col]
#pragma unroll
  for (int mf = 0; mf < 2; ++mf) {
    int row = n0 + wm * 32 + mf * 16 + kg * 4;
    f32x4 dr = *(const f32x4*)&dnorm[b * NDIM + row];
#pragma unroll
    for (int nf = 0; nf < 4; ++nf) {
      int col = wn * 64 + nf * 16 + lr;
      float bv = bias[col];
      float* op = out + ((size_t)b * NDIM + row) * FDIM + col;
#pragma unroll
      for (int j = 0; j < 4; ++j) op[(size_t)j * FDIM] = dr[j] * acc[mf][nf][j] + bv;
    }
  }
}

extern "C" void kernel_launch(void* const* d_in, const int* in_sizes, int n_in,
                              void* d_out, int out_size, void* d_ws, size_t ws_size,
                              hipStream_t stream) {
  (void)in_sizes; (void)n_in; (void)out_size; (void)ws_size;
  const float* input = (const float*)d_in[0];
  const float* adj = (const float*)d_in[1];
  const float* weight = (const float*)d_in[2];
  const float* bias = (const float*)d_in[3];
  float* out = (float*)d_out;

  char* ws = (char*)d_ws;
  short* st = (short*)ws;                                       // 8 MB  (bf16 S^T)
  float* dnorm = (float*)(ws + 8ull * 1024 * 1024);             // 64 KB
  float* part = (float*)(ws + 8ull * 1024 * 1024 + 65536);      // 2 MB
  short* wt = (short*)(ws + 8ull * 1024 * 1024 + 65536 + 2ull * 1024 * 1024);  // 128 KB
  short* abf = (short*)(ws + 16ull * 1024 * 1024);              // 64 MB (bf16 adj)

  k_colsum<<<dim3(BATCH * CH * 2), dim3(256), 0, stream>>>(adj, part, abf);
  k_dfin<<<dim3(BATCH * NDIM / 256), dim3(256), 0, stream>>>(part, dnorm);
  k_wt<<<dim3(16), dim3(256), 0, stream>>>(weight, wt);
  k_support<<<dim3(BATCH * (NDIM / 64)), dim3(256), 0, stream>>>(input, wt, dnorm, st);
  k_main<<<dim3(BATCH * (NDIM / 64)), dim3(512), 0, stream>>>(abf, st, dnorm, bias, out);
}